// Round 7
// baseline (397.640 us; speedup 1.0000x reference)
//
#include <hip/hip_runtime.h>

// Fused 3D SSIM, window 7^3, VALID. pred/targ: (4,1,32,320,320) f32.
// Tile = 16h x 32w outputs, 2 adjacent w-outputs per thread; t split in 4
// segments (7,7,6,6 outputs; 13/13/12/12 slices). No input LDS staging:
// colsum reads global directly (L1/L2-backed), register-prefetched one
// slice ahead. One barrier per slice; double-buffered colp.
// colp holds column-sum PAIRS (cols 2j,2j+1) per field as float2 —
// rowgather sums 4 pairs (8 cols) and subtracts one component per output.
// 4 tracked fields: f0=sum p, f1=sum q, f2=sum p^2+q^2, f3=sum p*q.

#define WIN 7
#define NPIX 343

constexpr int B = 4, T = 32, H = 320, W = 320;
constexpr int TO = T - 6, HO = H - 6, WO = W - 6;   // 26, 314, 314
constexpr long long NOUT = (long long)B * TO * HO * WO;

constexpr int TH = 16, TW = 32;      // output tile
constexpr int NTH = 20, NTW = 10;    // ceil(314/16), ceil(314/32)
constexpr int NSEG = 4;              // t segments: outputs 7,7,6,6
constexpr int C2P = 20;              // colp inner stride (float2 units)

__global__ __launch_bounds__(256, 4) void ssim3d_fused(
    const float* __restrict__ pred,
    const float* __restrict__ targ,
    const float* __restrict__ drange,
    double* __restrict__ acc)
{
    __shared__ float2 colp[2][4][TH][C2P];   // [buf][field][row][pair]
    __shared__ float wsum[4];

    const int bx  = blockIdx.x;
    const int b   = bx / (NSEG * NTH * NTW);
    int rem       = bx % (NSEG * NTH * NTW);
    const int seg = rem / (NTH * NTW);
    rem           = rem % (NTH * NTW);
    const int h0  = (rem / NTW) * TH;
    const int w0  = (rem % NTW) * TW;
    const int t0  = (seg < 3) ? seg * 7 : 20;
    const int ns  = (seg < 2) ? 13 : 12;     // slices this segment

    const int tid = threadIdx.x;
    const float* pb = pred + b * (T * H * W);
    const float* qb = targ + b * (T * H * W);

    // ---- colsum mapping: 152 items = 8 row-pairs x 19 col-pairs ----
    // rp = tid/19 keeps 19 consecutive lanes on one row -> coalesced f2 reads.
    const int rp  = tid / 19;
    const int cpi = tid % 19;
    const bool colw = (tid < 152);
    const int gc = min(w0 + 2 * cpi, W - 2);
    int idx[8];
#pragma unroll
    for (int dy = 0; dy < 8; ++dy)
        idx[dy] = min(h0 + 2 * rp + dy, H - 1) * W + gc;

    // ---- rowgather mapping: outputs (oh, 2k) and (oh, 2k+1) ----
    const int oh = tid >> 4, k = tid & 15;
    const bool vh = (h0 + oh < HO);
    const bool vE = vh && (w0 + 2 * k     < WO);
    const bool vO = vh && (w0 + 2 * k + 1 < WO);

    const float dr  = drange[b];
    const float C1v = (0.01f * dr) * (0.01f * dr);
    const float C2v = (0.03f * dr) * (0.03f * dr);
    const float inv  = 1.0f / (float)NPIX;
    const float covn = (float)NPIX / (float)(NPIX - 1);

    float rE[4][7], rO[4][7], tE[4], tO[4];
#pragma unroll
    for (int f = 0; f < 4; ++f) {
        tE[f] = tO[f] = 0.f;
#pragma unroll
        for (int j = 0; j < 7; ++j) { rE[f][j] = rO[f][j] = 0.f; }
    }
    float loss = 0.f;

    auto ssim1 = [&](const float* tt) {
        float ux  = tt[0] * inv, uy = tt[1] * inv;
        float u2  = tt[2] * inv, uxy = tt[3] * inv;
        float B2 = covn * (u2 - ux * ux - uy * uy) + C2v;
        float A2 = 2.f * covn * (uxy - ux * uy) + C2v;
        float A1 = 2.f * ux * uy + C1v;
        float B1 = ux * ux + uy * uy + C1v;
        return 1.f - __fdividef(A1 * A2, B1 * B2);
    };

    // register prefetch buffer: one slice (8 rows x pair, both fields)
    float2 pf[8], qf[8];
    auto loadSlice = [&](int s) {
        const int sb = (t0 + s) * (H * W);
#pragma unroll
        for (int dy = 0; dy < 8; ++dy) {
            pf[dy] = *reinterpret_cast<const float2*>(pb + sb + idx[dy]);
            qf[dy] = *reinterpret_cast<const float2*>(qb + sb + idx[dy]);
        }
    };

    if (colw) loadSlice(0);

    for (int a = 0; a < 14; a += 7) {
#pragma unroll
        for (int jj = 0; jj < 7; ++jj) {
            const int s = a + jj;
            if (s < ns) {
                const int bs = s & 1;

                if (colw) {
                    // colsum from prefetched regs: aA = rows 0..6, aB = rows 1..7
                    float2 aA[4], aB[4];
#pragma unroll
                    for (int dy = 0; dy < 8; ++dy) {
                        float2 p = pf[dy], q = qf[dy];
                        float2 v0 = p, v1 = q;
                        float2 v2 = make_float2(fmaf(p.x, p.x, q.x * q.x),
                                                fmaf(p.y, p.y, q.y * q.y));
                        float2 v3 = make_float2(p.x * q.x, p.y * q.y);
                        if (dy == 0) {
                            aA[0] = v0; aA[1] = v1; aA[2] = v2; aA[3] = v3;
                        } else if (dy == 1) {
                            aB[0] = v0; aB[1] = v1; aB[2] = v2; aB[3] = v3;
                            aA[0].x += v0.x; aA[0].y += v0.y;
                            aA[1].x += v1.x; aA[1].y += v1.y;
                            aA[2].x += v2.x; aA[2].y += v2.y;
                            aA[3].x += v3.x; aA[3].y += v3.y;
                        } else if (dy == 7) {
                            aB[0].x += v0.x; aB[0].y += v0.y;
                            aB[1].x += v1.x; aB[1].y += v1.y;
                            aB[2].x += v2.x; aB[2].y += v2.y;
                            aB[3].x += v3.x; aB[3].y += v3.y;
                        } else {
                            aA[0].x += v0.x; aA[0].y += v0.y;
                            aA[1].x += v1.x; aA[1].y += v1.y;
                            aA[2].x += v2.x; aA[2].y += v2.y;
                            aA[3].x += v3.x; aA[3].y += v3.y;
                            aB[0].x += v0.x; aB[0].y += v0.y;
                            aB[1].x += v1.x; aB[1].y += v1.y;
                            aB[2].x += v2.x; aB[2].y += v2.y;
                            aB[3].x += v3.x; aB[3].y += v3.y;
                        }
                    }
#pragma unroll
                    for (int f = 0; f < 4; ++f) {
                        colp[bs][f][2 * rp][cpi]     = aA[f];
                        colp[bs][f][2 * rp + 1][cpi] = aB[f];
                    }
                    // issue next slice's loads; complete during rowgather etc.
                    if (s + 1 < ns) loadSlice(s + 1);
                }

                __syncthreads();   // colp[bs] ready

                // rowgather: 8-wide pair sum, drop one component per output
                float sEv[4], sOv[4];
#pragma unroll
                for (int f = 0; f < 4; ++f) {
                    float2 P0 = colp[bs][f][oh][k];
                    float2 P1 = colp[bs][f][oh][k + 1];
                    float2 P2 = colp[bs][f][oh][k + 2];
                    float2 P3 = colp[bs][f][oh][k + 3];
                    float s8 = (P0.x + P0.y) + (P1.x + P1.y)
                             + (P2.x + P2.y) + (P3.x + P3.y);
                    sEv[f] = s8 - P3.y;
                    sOv[f] = s8 - P0.x;
                }
#pragma unroll
                for (int f = 0; f < 4; ++f) {
                    tE[f] += sEv[f] - rE[f][jj];  rE[f][jj] = sEv[f];
                    tO[f] += sOv[f] - rO[f][jj];  rO[f][jj] = sOv[f];
                }

                if (s >= 6) {
                    if (vE) loss += ssim1(tE);
                    if (vO) loss += ssim1(tO);
                }
            }
        }
    }

    // ---- block reduction -> global atomic ----
    for (int off = 32; off > 0; off >>= 1)
        loss += __shfl_down(loss, off, 64);
    const int lane = tid & 63;
    const int wid  = tid >> 6;
    if (lane == 0) wsum[wid] = loss;
    __syncthreads();
    if (tid == 0) {
        float s = wsum[0] + wsum[1] + wsum[2] + wsum[3];
        atomicAdd(acc, (double)s);
    }
}

__global__ void ssim3d_finalize(const double* __restrict__ acc,
                                float* __restrict__ out)
{
    out[0] = (float)(acc[0] / (double)NOUT);
}

extern "C" void kernel_launch(void* const* d_in, const int* in_sizes, int n_in,
                              void* d_out, int out_size, void* d_ws, size_t ws_size,
                              hipStream_t stream)
{
    const float* pred   = (const float*)d_in[0];
    const float* targ   = (const float*)d_in[1];
    const float* drange = (const float*)d_in[2];
    float* out  = (float*)d_out;
    double* acc = (double*)d_ws;

    hipMemsetAsync(acc, 0, sizeof(double), stream);

    const int nblocks = B * NSEG * NTH * NTW;  // 3200
    ssim3d_fused<<<nblocks, 256, 0, stream>>>(pred, targ, drange, acc);
    ssim3d_finalize<<<1, 1, 0, stream>>>(acc, out);
}

// Round 8
// 122.799 us; speedup vs baseline: 3.2381x; 3.2381x over previous
//
#include <hip/hip_runtime.h>

// Fused 3D SSIM, window 7^3, VALID. pred/targ: (4,1,32,320,320) f32.
// Tile = 16h x 32w outputs, 2 adjacent w-outputs per thread; t split in 2
// halves (13 outputs each, 19 slices). One barrier per slice, double-buffered
// sp/sq staging + colp (column-sum PAIRS per field as float2).
// 4 tracked fields: f0=sum p, f1=sum q, f2=sum p^2+q^2, f3=sum p*q.
// Per slice: commit staged slice s+1 | row-paired column sums of slice s
// from LDS -> colp | prefetch s+2 -> barrier -> rowgather (4 b64 pair reads
// per field, subtract one component per output) + temporal register ring.

#define WIN 7
#define NPIX 343

constexpr int B = 4, T = 32, H = 320, W = 320;
constexpr int TO = T - 6, HO = H - 6, WO = W - 6;   // 26, 314, 314
constexpr long long NOUT = (long long)B * TO * HO * WO;

constexpr int TH = 16, TW = 32;      // output tile
constexpr int IH = 22;               // input tile rows (+6 halo)
constexpr int SPW = 44;              // sp/sq row stride (16B-aligned rows)
constexpr int C2P = 20;              // colp inner stride (float2 units)
constexpr int NTH = 20, NTW = 10;    // ceil(314/16), ceil(314/32)
constexpr int OT_PER = 13, NS = OT_PER + 6;  // 19 slices per half

__global__ __launch_bounds__(256, 4) void ssim3d_fused(
    const float* __restrict__ pred,
    const float* __restrict__ targ,
    const float* __restrict__ drange,
    double* __restrict__ acc)
{
    __shared__ float sp[2][IH][SPW];
    __shared__ float sq[2][IH][SPW];
    __shared__ float2 colp[2][4][TH][C2P];   // [buf][field][row][pair]
    __shared__ float wsum[4];

    const int bx   = blockIdx.x;
    const int b    = bx / (2 * NTH * NTW);
    int rem        = bx % (2 * NTH * NTW);
    const int half = rem / (NTH * NTW);
    rem            = rem % (NTH * NTW);
    const int h0   = (rem / NTW) * TH;
    const int w0   = (rem % NTW) * TW;
    const int t0   = half * OT_PER;

    const int tid = threadIdx.x;

    const float* pb = pred + (long long)b * T * H * W;
    const float* qb = targ + (long long)b * T * H * W;

    // ---- staging: 440 float4 items = 2 fields x 22 rows x 10 f4-cols ----
    const int f0s = tid / 220, rm0 = tid % 220;
    const int r0s = rm0 / 10, c0s = rm0 % 10;
    const int gr0 = min(h0 + r0s, H - 1), gc0 = min(w0 + 4 * c0s, W - 4);
    const float* gb0 = (f0s ? qb : pb) + (long long)gr0 * W + gc0;
    const int o0 = r0s * SPW + 4 * c0s;

    const bool act1 = (tid < 184);
    const int item1 = 256 + tid;
    const int f1s = item1 / 220, rm1 = item1 % 220;
    const int r1s = rm1 / 10, c1s = rm1 % 10;
    const int gr1 = min(h0 + r1s, H - 1), gc1 = min(w0 + 4 * c1s, W - 4);
    const float* gb1 = (f1s ? qb : pb) + (long long)gr1 * W + gc1;
    const int o1 = r1s * SPW + 4 * c1s;

    float4 pr0, pr1;
    auto prefetchw = [&](int s) {
        const long long so = (long long)(t0 + s) * H * W;
        pr0 = *reinterpret_cast<const float4*>(gb0 + so);
        if (act1) pr1 = *reinterpret_cast<const float4*>(gb1 + so);
    };
    auto commitw = [&](int buf) {
        float* d0 = (f0s ? &sq[buf][0][0] : &sp[buf][0][0]) + o0;
        *reinterpret_cast<float4*>(d0) = pr0;
        if (act1) {
            float* d1 = (f1s ? &sq[buf][0][0] : &sp[buf][0][0]) + o1;
            *reinterpret_cast<float4*>(d1) = pr1;
        }
    };

    // ---- colsum mapping: 152 items = 8 row-pairs x 19 col-pairs ----
    // rp in low bits: wave's 8 rp x 8 cpi spread LDS bank bases.
    const bool colw = (tid < 152);
    const int rp  = tid & 7;          // row-pair 0..7
    const int cpi = tid >> 3;         // col-pair 0..18
    const int cr0 = 2 * rp;
    const int cc  = 2 * cpi;

    // ---- rowgather mapping: outputs (oh, 2k) and (oh, 2k+1) ----
    const int oh = tid >> 4, k = tid & 15;
    const bool vh = (h0 + oh < HO);
    const bool vE = vh && (w0 + 2 * k     < WO);
    const bool vO = vh && (w0 + 2 * k + 1 < WO);

    const float dr  = drange[b];
    const float C1v = (0.01f * dr) * (0.01f * dr);
    const float C2v = (0.03f * dr) * (0.03f * dr);
    const float inv  = 1.0f / (float)NPIX;
    const float covn = (float)NPIX / (float)(NPIX - 1);

    float rE[4][7], rO[4][7], tE[4], tO[4];
#pragma unroll
    for (int f = 0; f < 4; ++f) {
        tE[f] = tO[f] = 0.f;
#pragma unroll
        for (int j = 0; j < 7; ++j) { rE[f][j] = rO[f][j] = 0.f; }
    }
    float loss = 0.f;

    auto ssim1 = [&](const float* tt) {
        float ux  = tt[0] * inv, uy = tt[1] * inv;
        float u2  = tt[2] * inv, uxy = tt[3] * inv;
        float B2 = covn * (u2 - ux * ux - uy * uy) + C2v;
        float A2 = 2.f * covn * (uxy - ux * uy) + C2v;
        float A1 = 2.f * ux * uy + C1v;
        float B1 = ux * ux + uy * uy + C1v;
        return 1.f - __fdividef(A1 * A2, B1 * B2);
    };

    // ---- prologue ----
    prefetchw(0);
    commitw(0);
    prefetchw(1);
    __syncthreads();

    for (int a = 0; a < 21; a += 7) {
#pragma unroll
        for (int jj = 0; jj < 7; ++jj) {
            const int s = a + jj;
            if (s < NS) {
                const int bs = s & 1, bn = bs ^ 1;

                if (s + 1 < NS) commitw(bn);

                if (colw) {
                    // aA = rows cr0..cr0+6, aB = rows cr0+1..cr0+7 (shared mid)
                    float2 mid[4], row0[4], row7[4];
#pragma unroll
                    for (int dy = 0; dy < 8; ++dy) {
                        float2 p = *reinterpret_cast<const float2*>(&sp[bs][cr0 + dy][cc]);
                        float2 q = *reinterpret_cast<const float2*>(&sq[bs][cr0 + dy][cc]);
                        float2 v[4];
                        v[0] = p;
                        v[1] = q;
                        v[2] = make_float2(fmaf(p.x, p.x, q.x * q.x),
                                           fmaf(p.y, p.y, q.y * q.y));
                        v[3] = make_float2(p.x * q.x, p.y * q.y);
                        if (dy == 0) {
#pragma unroll
                            for (int f = 0; f < 4; ++f) row0[f] = v[f];
                        } else if (dy == 7) {
#pragma unroll
                            for (int f = 0; f < 4; ++f) row7[f] = v[f];
                        } else if (dy == 1) {
#pragma unroll
                            for (int f = 0; f < 4; ++f) mid[f] = v[f];
                        } else {
#pragma unroll
                            for (int f = 0; f < 4; ++f) {
                                mid[f].x += v[f].x; mid[f].y += v[f].y;
                            }
                        }
                    }
#pragma unroll
                    for (int f = 0; f < 4; ++f) {
                        // pair (cols cc, cc+1) for rows cr0 and cr0+1
                        colp[bs][f][cr0][cpi] =
                            make_float2(row0[f].x + mid[f].x, row0[f].y + mid[f].y);
                        colp[bs][f][cr0 + 1][cpi] =
                            make_float2(mid[f].x + row7[f].x, mid[f].y + row7[f].y);
                    }
                }

                if (s + 2 < NS) prefetchw(s + 2);

                __syncthreads();   // colp[bs] ready; sp[bn] committed

                // ---- rowgather: 8-wide pair sum, drop one component per output
                float sEv[4], sOv[4];
#pragma unroll
                for (int f = 0; f < 4; ++f) {
                    float2 P0 = colp[bs][f][oh][k];
                    float2 P1 = colp[bs][f][oh][k + 1];
                    float2 P2 = colp[bs][f][oh][k + 2];
                    float2 P3 = colp[bs][f][oh][k + 3];
                    float s8 = (P0.x + P0.y) + (P1.x + P1.y)
                             + (P2.x + P2.y) + (P3.x + P3.y);
                    sEv[f] = s8 - P3.y;
                    sOv[f] = s8 - P0.x;
                }
#pragma unroll
                for (int f = 0; f < 4; ++f) {
                    tE[f] += sEv[f] - rE[f][jj];  rE[f][jj] = sEv[f];
                    tO[f] += sOv[f] - rO[f][jj];  rO[f][jj] = sOv[f];
                }

                if (s >= 6) {
                    if (vE) loss += ssim1(tE);
                    if (vO) loss += ssim1(tO);
                }
            }
        }
    }

    // ---- block reduction -> global atomic ----
    for (int off = 32; off > 0; off >>= 1)
        loss += __shfl_down(loss, off, 64);
    const int lane = tid & 63;
    const int wid  = tid >> 6;
    if (lane == 0) wsum[wid] = loss;
    __syncthreads();
    if (tid == 0) {
        float s = wsum[0] + wsum[1] + wsum[2] + wsum[3];
        atomicAdd(acc, (double)s);
    }
}

__global__ void ssim3d_finalize(const double* __restrict__ acc,
                                float* __restrict__ out)
{
    out[0] = (float)(acc[0] / (double)NOUT);
}

extern "C" void kernel_launch(void* const* d_in, const int* in_sizes, int n_in,
                              void* d_out, int out_size, void* d_ws, size_t ws_size,
                              hipStream_t stream)
{
    const float* pred   = (const float*)d_in[0];
    const float* targ   = (const float*)d_in[1];
    const float* drange = (const float*)d_in[2];
    float* out  = (float*)d_out;
    double* acc = (double*)d_ws;

    hipMemsetAsync(acc, 0, sizeof(double), stream);

    const int nblocks = B * 2 * NTH * NTW;  // 1600
    ssim3d_fused<<<nblocks, 256, 0, stream>>>(pred, targ, drange, acc);
    ssim3d_finalize<<<1, 1, 0, stream>>>(acc, out);
}

// Round 9
// 107.525 us; speedup vs baseline: 3.6981x; 1.1421x over previous
//
#include <hip/hip_runtime.h>

// Fused 3D SSIM, window 7^3, VALID. pred/targ: (4,1,32,320,320) f32.
// Round-5 structure (proven 83us) + XCD-chunked block swizzle (each XCD's
// 200-block chunk = one full (batch, t-half) spatial tiling -> halos L2-hit
// within the XCD) + 2-deep register prefetch (issue slice X at X-3, commit
// at X-1) to cover cold-HBM latency.
// Tile = 16h x 32w outputs, 2 adjacent w-outputs per thread; t split in 2
// halves (13 outputs each, 19 slices). One barrier per slice; double-buffered
// sp/sq + col/col2. 4 tracked fields: f0=sum p, f1=sum q, f2=sum p^2+q^2,
// f3=sum p*q.

#define WIN 7
#define NPIX 343

constexpr int B = 4, T = 32, H = 320, W = 320;
constexpr int TO = T - 6, HO = H - 6, WO = W - 6;   // 26, 314, 314
constexpr long long NOUT = (long long)B * TO * HO * WO;

constexpr int TH = 16, TW = 32;      // output tile
constexpr int IH = 22;               // input tile rows (+6 halo)
constexpr int SPW = 44;              // sp/sq row stride (f4-aligned, bank-spread)
constexpr int CW  = 41;              // col row stride (odd: rows alternate parity)
constexpr int C2W = 24;              // col2 row stride
constexpr int NTH = 20, NTW = 10;    // ceil(314/16), ceil(314/32)
constexpr int OT_PER = 13, NS = OT_PER + 6;  // 19 slices per half
constexpr int NBLK = B * 2 * NTH * NTW;      // 1600
constexpr int CPX  = NBLK / 8;               // 200 blocks per XCD chunk

__global__ __launch_bounds__(256) void ssim3d_fused(
    const float* __restrict__ pred,
    const float* __restrict__ targ,
    const float* __restrict__ drange,
    double* __restrict__ acc)
{
    __shared__ float sp[2][IH][SPW];
    __shared__ float sq[2][IH][SPW];
    __shared__ float col [2][4][TH][CW];
    __shared__ float col2[2][4][TH][C2W];
    __shared__ float wsum[4];

    // XCD-chunked bijective swizzle (1600 % 8 == 0).
    const int bid = blockIdx.x;
    const int bx  = (bid & 7) * CPX + (bid >> 3);

    const int b    = bx / (2 * NTH * NTW);
    int rem        = bx % (2 * NTH * NTW);
    const int half = rem / (NTH * NTW);
    rem            = rem % (NTH * NTW);
    const int h0   = (rem / NTW) * TH;
    const int w0   = (rem % NTW) * TW;
    const int t0   = half * OT_PER;

    const int tid = threadIdx.x;

    const float* pb = pred + (long long)b * T * H * W;
    const float* qb = targ + (long long)b * T * H * W;

    // ---- staging: 440 float4 items = 2 fields x 22 rows x 10 f4-cols ----
    const int f0s = tid / 220, rm0 = tid % 220;
    const int r0s = rm0 / 10, c0s = rm0 % 10;
    const int gr0 = min(h0 + r0s, H - 1), gc0 = min(w0 + 4 * c0s, W - 4);
    const float* gb0 = (f0s ? qb : pb) + (long long)gr0 * W + gc0;
    const int o0 = r0s * SPW + 4 * c0s;

    const bool act1 = (tid < 184);
    const int item1 = 256 + tid;
    const int f1s = item1 / 220, rm1 = item1 % 220;
    const int r1s = rm1 / 10, c1s = rm1 % 10;
    const int gr1 = min(h0 + r1s, H - 1), gc1 = min(w0 + 4 * c1s, W - 4);
    const float* gb1 = (f1s ? qb : pb) + (long long)gr1 * W + gc1;
    const int o1 = r1s * SPW + 4 * c1s;

    // two in-flight register sets: data for slice X lives in set X&1
    float4 prA0, prA1, prB0, prB1;
    auto prefetchw = [&](int s, int set) {
        const long long so = (long long)(t0 + s) * H * W;
        if (set == 0) {
            prA0 = *reinterpret_cast<const float4*>(gb0 + so);
            if (act1) prA1 = *reinterpret_cast<const float4*>(gb1 + so);
        } else {
            prB0 = *reinterpret_cast<const float4*>(gb0 + so);
            if (act1) prB1 = *reinterpret_cast<const float4*>(gb1 + so);
        }
    };
    auto commitw = [&](int buf, int set) {
        float* d0 = (f0s ? &sq[buf][0][0] : &sp[buf][0][0]) + o0;
        float* d1 = (f1s ? &sq[buf][0][0] : &sp[buf][0][0]) + o1;
        if (set == 0) {
            *reinterpret_cast<float4*>(d0) = prA0;
            if (act1) *reinterpret_cast<float4*>(d1) = prA1;
        } else {
            *reinterpret_cast<float4*>(d0) = prB0;
            if (act1) *reinterpret_cast<float4*>(d1) = prB1;
        }
    };

    // ---- colsum mapping: 152 items = 8 row-pairs x 19 col-pairs ----
    const bool colw = (tid < 152);
    const int rp = tid / 19, cpi = tid % 19;
    const int cr0 = 2 * rp;
    const int cc  = 2 * cpi;

    // ---- rowgather mapping: outputs (oh, 2k) and (oh, 2k+1) ----
    const int oh = tid >> 4, k = tid & 15;
    const bool vh = (h0 + oh < HO);
    const bool vE = vh && (w0 + 2 * k     < WO);
    const bool vO = vh && (w0 + 2 * k + 1 < WO);

    const float dr  = drange[b];
    const float C1v = (0.01f * dr) * (0.01f * dr);
    const float C2v = (0.03f * dr) * (0.03f * dr);
    const float inv  = 1.0f / (float)NPIX;
    const float covn = (float)NPIX / (float)(NPIX - 1);

    float rE[4][7], rO[4][7], tE[4], tO[4];
#pragma unroll
    for (int f = 0; f < 4; ++f) {
        tE[f] = tO[f] = 0.f;
#pragma unroll
        for (int j = 0; j < 7; ++j) { rE[f][j] = rO[f][j] = 0.f; }
    }
    float loss = 0.f;

    auto ssim1 = [&](const float* tt) {
        float ux  = tt[0] * inv, uy = tt[1] * inv;
        float u2  = tt[2] * inv, uxy = tt[3] * inv;
        float B2 = covn * (u2 - ux * ux - uy * uy) + C2v;
        float A2 = 2.f * covn * (uxy - ux * uy) + C2v;
        float A1 = 2.f * ux * uy + C1v;
        float B1 = ux * ux + uy * uy + C1v;
        return 1.f - (A1 * A2) / (B1 * B2);
    };

    // ---- prologue: slices 0,1 in flight; commit 0; issue 2 ----
    prefetchw(0, 0);
    prefetchw(1, 1);
    commitw(0, 0);
    prefetchw(2, 0);
    __syncthreads();

    for (int a = 0; a < 21; a += 7) {
#pragma unroll
        for (int jj = 0; jj < 7; ++jj) {
            const int s = a + jj;
            if (s < NS) {
                const int bs = s & 1, bn = bs ^ 1;

                // commit slice s+1 (issued at s-2; set index (s+1)&1 == bn)
                if (s + 1 < NS) commitw(bn, bn);

                if (colw) {
                    float2 mid[4], row0[4], row7[4];
#pragma unroll
                    for (int dy = 0; dy < 8; ++dy) {
                        float2 p = *reinterpret_cast<const float2*>(&sp[bs][cr0 + dy][cc]);
                        float2 q = *reinterpret_cast<const float2*>(&sq[bs][cr0 + dy][cc]);
                        float2 v[4];
                        v[0] = p;
                        v[1] = q;
                        v[2] = make_float2(fmaf(p.x, p.x, q.x * q.x),
                                           fmaf(p.y, p.y, q.y * q.y));
                        v[3] = make_float2(p.x * q.x, p.y * q.y);
                        if (dy == 0) {
#pragma unroll
                            for (int f = 0; f < 4; ++f) row0[f] = v[f];
                        } else if (dy == 7) {
#pragma unroll
                            for (int f = 0; f < 4; ++f) row7[f] = v[f];
                        } else if (dy == 1) {
#pragma unroll
                            for (int f = 0; f < 4; ++f) mid[f] = v[f];
                        } else {
#pragma unroll
                            for (int f = 0; f < 4; ++f) {
                                mid[f].x += v[f].x; mid[f].y += v[f].y;
                            }
                        }
                    }
#pragma unroll
                    for (int f = 0; f < 4; ++f) {
                        float ax  = row0[f].x + mid[f].x;   // (row cr0,   col cc)
                        float ay  = row0[f].y + mid[f].y;   // (row cr0,   col cc+1)
                        float bxv = mid[f].x + row7[f].x;   // (row cr0+1, col cc)
                        float byv = mid[f].y + row7[f].y;   // (row cr0+1, col cc+1)
                        col[bs][f][cr0][cc]         = ax;
                        col[bs][f][cr0][cc + 1]     = ay;
                        col[bs][f][cr0 + 1][cc]     = bxv;
                        col[bs][f][cr0 + 1][cc + 1] = byv;
                        col2[bs][f][cr0][cpi]     = ax + ay;
                        col2[bs][f][cr0 + 1][cpi] = bxv + byv;
                    }
                }

                // issue slice s+3 into set (s+3)&1 == bn (regs just committed)
                if (s + 3 < NS) prefetchw(s + 3, bn);

                __syncthreads();   // col[bs] ready; sp[bn] committed

                // ---- rowgather: S8 via 4 pairs, then 2 outputs via singles
                float sEv[4], sOv[4];
#pragma unroll
                for (int f = 0; f < 4; ++f) {
                    const float* c2r = &col2[bs][f][oh][0];
                    float s8 = c2r[k] + c2r[k + 1] + c2r[k + 2] + c2r[k + 3];
                    const float* cr = &col[bs][f][oh][0];
                    sEv[f] = s8 - cr[2 * k + 7];
                    sOv[f] = s8 - cr[2 * k];
                }
#pragma unroll
                for (int f = 0; f < 4; ++f) {
                    tE[f] += sEv[f] - rE[f][jj];  rE[f][jj] = sEv[f];
                    tO[f] += sOv[f] - rO[f][jj];  rO[f][jj] = sOv[f];
                }

                if (s >= 6) {
                    if (vE) loss += ssim1(tE);
                    if (vO) loss += ssim1(tO);
                }
            }
        }
    }

    // ---- block reduction -> global atomic ----
    for (int off = 32; off > 0; off >>= 1)
        loss += __shfl_down(loss, off, 64);
    const int lane = tid & 63;
    const int wid  = tid >> 6;
    if (lane == 0) wsum[wid] = loss;
    __syncthreads();
    if (tid == 0) {
        float s = wsum[0] + wsum[1] + wsum[2] + wsum[3];
        atomicAdd(acc, (double)s);
    }
}

__global__ void ssim3d_finalize(const double* __restrict__ acc,
                                float* __restrict__ out)
{
    out[0] = (float)(acc[0] / (double)NOUT);
}

extern "C" void kernel_launch(void* const* d_in, const int* in_sizes, int n_in,
                              void* d_out, int out_size, void* d_ws, size_t ws_size,
                              hipStream_t stream)
{
    const float* pred   = (const float*)d_in[0];
    const float* targ   = (const float*)d_in[1];
    const float* drange = (const float*)d_in[2];
    float* out  = (float*)d_out;
    double* acc = (double*)d_ws;

    hipMemsetAsync(acc, 0, sizeof(double), stream);

    ssim3d_fused<<<NBLK, 256, 0, stream>>>(pred, targ, drange, acc);
    ssim3d_finalize<<<1, 1, 0, stream>>>(acc, out);
}

// Round 10
// 91.005 us; speedup vs baseline: 4.3694x; 1.1815x over previous
//
#include <hip/hip_runtime.h>

// Fused 3D SSIM, window 7^3, VALID. pred/targ: (4,1,32,320,320) f32.
// Golden round-5 structure (85us) with field-pair (float2) packed column
// arrays: colfp[col] = (field_a(col), field_b(col)); col2fp[pair] =
// pair-sum per field-pair. Halves LDS instruction count in colsum-write
// and rowgather phases. Tile = 16h x 32w outputs, 2 adjacent w-outputs
// per thread; t split in 2 halves (13 outputs, 19 slices). One barrier
// per slice; double-buffered sp/sq + colfp/col2fp. Fields: f0=sum p,
// f1=sum q, f2=sum p^2+q^2, f3=sum p*q.

#define WIN 7
#define NPIX 343

constexpr int B = 4, T = 32, H = 320, W = 320;
constexpr int TO = T - 6, HO = H - 6, WO = W - 6;   // 26, 314, 314
constexpr long long NOUT = (long long)B * TO * HO * WO;

constexpr int TH = 16, TW = 32;      // output tile
constexpr int IH = 22;               // input tile rows (+6 halo)
constexpr int SPW = 44;              // sp/sq row stride (proven banks)
constexpr int CFW = 40;              // colfp inner stride (float2 units)
constexpr int C2W = 20;              // col2fp inner stride (float2 units)
constexpr int NTH = 20, NTW = 10;    // ceil(314/16), ceil(314/32)
constexpr int OT_PER = 13, NS = OT_PER + 6;  // 19 slices per half

__global__ __launch_bounds__(256) void ssim3d_fused(
    const float* __restrict__ pred,
    const float* __restrict__ targ,
    const float* __restrict__ drange,
    double* __restrict__ acc)
{
    __shared__ float sp[2][IH][SPW];              // 7744 B x2
    __shared__ float sq[2][IH][SPW];
    __shared__ float2 colfp [2][2][TH][CFW];      // 20480 B [buf][fp][row][col]
    __shared__ float2 col2fp[2][2][TH][C2W];      // 10240 B [buf][fp][row][pair]
    __shared__ float wsum[4];

    const int bx   = blockIdx.x;
    const int b    = bx / (2 * NTH * NTW);
    int rem        = bx % (2 * NTH * NTW);
    const int half = rem / (NTH * NTW);
    rem            = rem % (NTH * NTW);
    const int h0   = (rem / NTW) * TH;
    const int w0   = (rem % NTW) * TW;
    const int t0   = half * OT_PER;

    const int tid = threadIdx.x;

    const float* pb = pred + (long long)b * T * H * W;
    const float* qb = targ + (long long)b * T * H * W;

    // ---- staging: 440 float4 items = 2 fields x 22 rows x 10 f4-cols ----
    const int f0s = tid / 220, rm0 = tid % 220;
    const int r0s = rm0 / 10, c0s = rm0 % 10;
    const int gr0 = min(h0 + r0s, H - 1), gc0 = min(w0 + 4 * c0s, W - 4);
    const float* gb0 = (f0s ? qb : pb) + (long long)gr0 * W + gc0;
    const int o0 = r0s * SPW + 4 * c0s;

    const bool act1 = (tid < 184);
    const int item1 = 256 + tid;
    const int f1s = item1 / 220, rm1 = item1 % 220;
    const int r1s = rm1 / 10, c1s = rm1 % 10;
    const int gr1 = min(h0 + r1s, H - 1), gc1 = min(w0 + 4 * c1s, W - 4);
    const float* gb1 = (f1s ? qb : pb) + (long long)gr1 * W + gc1;
    const int o1 = r1s * SPW + 4 * c1s;

    float4 pr0, pr1;
    auto prefetchw = [&](int s) {
        const long long so = (long long)(t0 + s) * H * W;
        pr0 = *reinterpret_cast<const float4*>(gb0 + so);
        if (act1) pr1 = *reinterpret_cast<const float4*>(gb1 + so);
    };
    auto commitw = [&](int buf) {
        float* d0 = (f0s ? &sq[buf][0][0] : &sp[buf][0][0]) + o0;
        *reinterpret_cast<float4*>(d0) = pr0;
        if (act1) {
            float* d1 = (f1s ? &sq[buf][0][0] : &sp[buf][0][0]) + o1;
            *reinterpret_cast<float4*>(d1) = pr1;
        }
    };

    // ---- colsum mapping: 152 items = 8 row-pairs x 19 col-pairs ----
    const bool colw = (tid < 152);
    const int rp = tid / 19, cpi = tid % 19;
    const int cr0 = 2 * rp;
    const int cc  = 2 * cpi;

    // ---- rowgather mapping: outputs (oh, 2k) and (oh, 2k+1) ----
    const int oh = tid >> 4, k = tid & 15;
    const bool vh = (h0 + oh < HO);
    const bool vE = vh && (w0 + 2 * k     < WO);
    const bool vO = vh && (w0 + 2 * k + 1 < WO);

    const float dr  = drange[b];
    const float C1v = (0.01f * dr) * (0.01f * dr);
    const float C2v = (0.03f * dr) * (0.03f * dr);
    const float inv  = 1.0f / (float)NPIX;
    const float covn = (float)NPIX / (float)(NPIX - 1);

    float rE[4][7], rO[4][7], tE[4], tO[4];
#pragma unroll
    for (int f = 0; f < 4; ++f) {
        tE[f] = tO[f] = 0.f;
#pragma unroll
        for (int j = 0; j < 7; ++j) { rE[f][j] = rO[f][j] = 0.f; }
    }
    float loss = 0.f;

    auto ssim1 = [&](const float* tt) {
        float ux  = tt[0] * inv, uy = tt[1] * inv;
        float u2  = tt[2] * inv, uxy = tt[3] * inv;
        float B2 = covn * (u2 - ux * ux - uy * uy) + C2v;
        float A2 = 2.f * covn * (uxy - ux * uy) + C2v;
        float A1 = 2.f * ux * uy + C1v;
        float B1 = ux * ux + uy * uy + C1v;
        return 1.f - (A1 * A2) / (B1 * B2);
    };

    // ---- prologue ----
    prefetchw(0);
    commitw(0);
    prefetchw(1);
    __syncthreads();

    for (int a = 0; a < 21; a += 7) {
#pragma unroll
        for (int jj = 0; jj < 7; ++jj) {
            const int s = a + jj;
            if (s < NS) {
                const int bs = s & 1, bn = bs ^ 1;

                if (s + 1 < NS) commitw(bn);

                if (colw) {
                    float2 mid[4], row0[4], row7[4];
#pragma unroll
                    for (int dy = 0; dy < 8; ++dy) {
                        float2 p = *reinterpret_cast<const float2*>(&sp[bs][cr0 + dy][cc]);
                        float2 q = *reinterpret_cast<const float2*>(&sq[bs][cr0 + dy][cc]);
                        float2 v[4];
                        v[0] = p;
                        v[1] = q;
                        v[2] = make_float2(fmaf(p.x, p.x, q.x * q.x),
                                           fmaf(p.y, p.y, q.y * q.y));
                        v[3] = make_float2(p.x * q.x, p.y * q.y);
                        if (dy == 0) {
#pragma unroll
                            for (int f = 0; f < 4; ++f) row0[f] = v[f];
                        } else if (dy == 7) {
#pragma unroll
                            for (int f = 0; f < 4; ++f) row7[f] = v[f];
                        } else if (dy == 1) {
#pragma unroll
                            for (int f = 0; f < 4; ++f) mid[f] = v[f];
                        } else {
#pragma unroll
                            for (int f = 0; f < 4; ++f) {
                                mid[f].x += v[f].x; mid[f].y += v[f].y;
                            }
                        }
                    }
                    float axf[4], ayf[4], bxf[4], byf[4];
#pragma unroll
                    for (int f = 0; f < 4; ++f) {
                        axf[f] = row0[f].x + mid[f].x;   // (row cr0,   col cc)
                        ayf[f] = row0[f].y + mid[f].y;   // (row cr0,   col cc+1)
                        bxf[f] = mid[f].x + row7[f].x;   // (row cr0+1, col cc)
                        byf[f] = mid[f].y + row7[f].y;   // (row cr0+1, col cc+1)
                    }
#pragma unroll
                    for (int fp = 0; fp < 2; ++fp) {
                        const int fa = 2 * fp, fb = 2 * fp + 1;
                        colfp[bs][fp][cr0][cc]         = make_float2(axf[fa], axf[fb]);
                        colfp[bs][fp][cr0][cc + 1]     = make_float2(ayf[fa], ayf[fb]);
                        colfp[bs][fp][cr0 + 1][cc]     = make_float2(bxf[fa], bxf[fb]);
                        colfp[bs][fp][cr0 + 1][cc + 1] = make_float2(byf[fa], byf[fb]);
                        col2fp[bs][fp][cr0][cpi] =
                            make_float2(axf[fa] + ayf[fa], axf[fb] + ayf[fb]);
                        col2fp[bs][fp][cr0 + 1][cpi] =
                            make_float2(bxf[fa] + byf[fa], bxf[fb] + byf[fb]);
                    }
                }

                if (s + 2 < NS) prefetchw(s + 2);

                __syncthreads();   // colfp/col2fp[bs] ready; sp[bn] committed

                // ---- rowgather: S8 via 4 pair reads (b64, 2 fields each),
                //      edges from packed singles (b64, 2 fields each)
                float sEv[4], sOv[4];
#pragma unroll
                for (int fp = 0; fp < 2; ++fp) {
                    const float2* c2r = &col2fp[bs][fp][oh][0];
                    float2 p0 = c2r[k], p1 = c2r[k + 1];
                    float2 p2 = c2r[k + 2], p3 = c2r[k + 3];
                    float s8x = (p0.x + p1.x) + (p2.x + p3.x);
                    float s8y = (p0.y + p1.y) + (p2.y + p3.y);
                    float2 eH = colfp[bs][fp][oh][2 * k + 7];
                    float2 eL = colfp[bs][fp][oh][2 * k];
                    sEv[2 * fp]     = s8x - eH.x;
                    sEv[2 * fp + 1] = s8y - eH.y;
                    sOv[2 * fp]     = s8x - eL.x;
                    sOv[2 * fp + 1] = s8y - eL.y;
                }
#pragma unroll
                for (int f = 0; f < 4; ++f) {
                    tE[f] += sEv[f] - rE[f][jj];  rE[f][jj] = sEv[f];
                    tO[f] += sOv[f] - rO[f][jj];  rO[f][jj] = sOv[f];
                }

                if (s >= 6) {
                    if (vE) loss += ssim1(tE);
                    if (vO) loss += ssim1(tO);
                }
            }
        }
    }

    // ---- block reduction -> global atomic ----
    for (int off = 32; off > 0; off >>= 1)
        loss += __shfl_down(loss, off, 64);
    const int lane = tid & 63;
    const int wid  = tid >> 6;
    if (lane == 0) wsum[wid] = loss;
    __syncthreads();
    if (tid == 0) {
        float s = wsum[0] + wsum[1] + wsum[2] + wsum[3];
        atomicAdd(acc, (double)s);
    }
}

__global__ void ssim3d_finalize(const double* __restrict__ acc,
                                float* __restrict__ out)
{
    out[0] = (float)(acc[0] / (double)NOUT);
}

extern "C" void kernel_launch(void* const* d_in, const int* in_sizes, int n_in,
                              void* d_out, int out_size, void* d_ws, size_t ws_size,
                              hipStream_t stream)
{
    const float* pred   = (const float*)d_in[0];
    const float* targ   = (const float*)d_in[1];
    const float* drange = (const float*)d_in[2];
    float* out  = (float*)d_out;
    double* acc = (double*)d_ws;

    hipMemsetAsync(acc, 0, sizeof(double), stream);

    const int nblocks = B * 2 * NTH * NTW;  // 1600
    ssim3d_fused<<<nblocks, 256, 0, stream>>>(pred, targ, drange, acc);
    ssim3d_finalize<<<1, 1, 0, stream>>>(acc, out);
}

// Round 11
// 87.854 us; speedup vs baseline: 4.5262x; 1.0359x over previous
//
#include <hip/hip_runtime.h>

// Fused 3D SSIM, window 7^3, VALID. pred/targ: (4,1,32,320,320) f32.
// Shuffle-gather structure: tile = 16h x 26w outputs, FULL t-range per
// block. Per slice: stage 22x32x2 tile (f2, double-buffered, prefetch
// 1 ahead) -> each thread (oh,k) computes pair-colsum (cols 2k,2k+1 over
// rows oh..oh+6) of 4 fields from LDS -> 7-wide w-sums assembled IN
// REGISTERS via intra-16-lane shuffles (no col arrays, no rowgather
// phase) -> temporal 7-ring in registers -> SSIM. One barrier per slice.
// Fields: f0=sum p, f1=sum q, f2=sum p^2+q^2, f3=sum p*q.

#define NPIX 343

constexpr int B = 4, T = 32, H = 320, W = 320;
constexpr int TO = T - 6, HO = H - 6, WO = W - 6;   // 26, 314, 314
constexpr long long NOUT = (long long)B * TO * HO * WO;

constexpr int TH = 16, TW = 26;    // output tile (26 = 13 pair-outputs k<=12)
constexpr int IH = 22, IW = 32;    // input tile: 22 rows x 32 cols (16 pairs)
constexpr int NTH = 20, NTW = 13;  // 20*16=320 >= 314; 13*26=338 >= 314
constexpr int NS = 32;             // all t slices per block

__global__ __launch_bounds__(256) void ssim3d_fused(
    const float* __restrict__ pred,
    const float* __restrict__ targ,
    const float* __restrict__ drange,
    double* __restrict__ acc)
{
    __shared__ float sp[2][IH][IW];   // 5632 B
    __shared__ float sq[2][IH][IW];   // 5632 B
    __shared__ float wsum[4];

    const int bx = blockIdx.x;
    const int b  = bx / (NTH * NTW);
    int rem      = bx % (NTH * NTW);
    const int h0 = (rem / NTW) * TH;
    const int w0 = (rem % NTW) * TW;

    const int tid = threadIdx.x;
    const int oh  = tid >> 4;   // 0..15 output row
    const int k   = tid & 15;   // pair-column 0..15 (outputs only k<=12)

    const float* pb = pred + (long long)b * T * H * W;
    const float* qb = targ + (long long)b * T * H * W;

    // ---- staging: 704 float2 items = 2 fields x 22 rows x 16 pair-cols ----
    // item i: f = (i>=352), rm = i - 352f, r = rm>>4, c = rm&15
    // item0 = tid        -> field p, r=oh, c=k
    // item1 = tid+256    -> field p if tid<96 else q
    // item2 = tid+512    -> field q (active tid<192)
    const int  i1  = tid + 256;
    const bool f1  = (i1 >= 352);
    const int  rm1 = i1 - (f1 ? 352 : 0);
    const int  r1  = rm1 >> 4, c1 = rm1 & 15;
    const bool act2 = (tid < 192);
    const int  rm2 = tid + 160;               // item2 field q
    const int  r2  = rm2 >> 4, c2 = rm2 & 15;

    const int gr0 = min(h0 + oh, H - 1), gc0 = min(w0 + 2 * k,  W - 2);
    const int gr1 = min(h0 + r1, H - 1), gc1 = min(w0 + 2 * c1, W - 2);
    const int gr2 = min(h0 + r2, H - 1), gc2 = min(w0 + 2 * c2, W - 2);
    const float* gp0 = pb + (long long)gr0 * W + gc0;
    const float* gp1 = (f1 ? qb : pb) + (long long)gr1 * W + gc1;
    const float* gp2 = qb + (long long)gr2 * W + gc2;
    const int o0 = oh * IW + 2 * k;
    const int o1 = r1 * IW + 2 * c1;
    const int o2 = r2 * IW + 2 * c2;

    float2 d0, d1, d2;
    auto prefetchw = [&](int s) {
        const long long so = (long long)s * H * W;
        d0 = *reinterpret_cast<const float2*>(gp0 + so);
        d1 = *reinterpret_cast<const float2*>(gp1 + so);
        if (act2) d2 = *reinterpret_cast<const float2*>(gp2 + so);
    };
    auto commitw = [&](int buf) {
        *reinterpret_cast<float2*>(&sp[buf][0][0] + o0) = d0;
        *reinterpret_cast<float2*>((f1 ? &sq[buf][0][0] : &sp[buf][0][0]) + o1) = d1;
        if (act2) *reinterpret_cast<float2*>(&sq[buf][0][0] + o2) = d2;
    };

    // ---- output validity ----
    const bool vh = (h0 + oh < HO);
    const bool emitk = (k <= 12);
    const bool vE = vh && emitk && (w0 + 2 * k     < WO);
    const bool vO = vh && emitk && (w0 + 2 * k + 1 < WO);

    const float dr  = drange[b];
    const float C1v = (0.01f * dr) * (0.01f * dr);
    const float C2v = (0.03f * dr) * (0.03f * dr);
    const float inv  = 1.0f / (float)NPIX;
    const float covn = (float)NPIX / (float)(NPIX - 1);

    float rE[4][7], rO[4][7], tE[4], tO[4];
#pragma unroll
    for (int f = 0; f < 4; ++f) {
        tE[f] = tO[f] = 0.f;
#pragma unroll
        for (int j = 0; j < 7; ++j) { rE[f][j] = rO[f][j] = 0.f; }
    }
    float loss = 0.f;

    auto ssim1 = [&](const float* tt) {
        float ux  = tt[0] * inv, uy = tt[1] * inv;
        float u2  = tt[2] * inv, uxy = tt[3] * inv;
        float B2 = covn * (u2 - ux * ux - uy * uy) + C2v;
        float A2 = 2.f * covn * (uxy - ux * uy) + C2v;
        float A1 = 2.f * ux * uy + C1v;
        float B1 = ux * ux + uy * uy + C1v;
        return 1.f - __fdividef(A1 * A2, B1 * B2);
    };

    // ---- prologue ----
    prefetchw(0);
    commitw(0);
    prefetchw(1);
    __syncthreads();

    for (int a = 0; a < NS; a += 7) {
#pragma unroll
        for (int jj = 0; jj < 7; ++jj) {
            const int s = a + jj;
            if (s < NS) {
                const int bs = s & 1, bn = bs ^ 1;

                // commit slice s+1 (loaded at s-1) into the other buffer
                if (s + 1 < NS) commitw(bn);

                // ---- per-thread pair-colsum: cols (2k,2k+1), rows oh..oh+6
                float cA[4] = {0.f, 0.f, 0.f, 0.f};
                float cB[4] = {0.f, 0.f, 0.f, 0.f};
#pragma unroll
                for (int dy = 0; dy < 7; ++dy) {
                    float2 p = *reinterpret_cast<const float2*>(&sp[bs][oh + dy][2 * k]);
                    float2 q = *reinterpret_cast<const float2*>(&sq[bs][oh + dy][2 * k]);
                    cA[0] += p.x;  cB[0] += p.y;
                    cA[1] += q.x;  cB[1] += q.y;
                    cA[2] = fmaf(p.x, p.x, cA[2]);  cA[2] = fmaf(q.x, q.x, cA[2]);
                    cB[2] = fmaf(p.y, p.y, cB[2]);  cB[2] = fmaf(q.y, q.y, cB[2]);
                    cA[3] = fmaf(p.x, q.x, cA[3]);
                    cB[3] = fmaf(p.y, q.y, cB[3]);
                }

                // issue next slice's global loads (consumed at s+2's commit)
                if (s + 2 < NS) prefetchw(s + 2);

                __syncthreads();   // sp[bn] committed; sp[bs] reads done

                // ---- in-register w-gather via intra-row shuffles ----
                float sEv[4], sOv[4];
#pragma unroll
                for (int f = 0; f < 4; ++f) {
                    float ps = cA[f] + cB[f];
                    float s4 = ps + __shfl_down(ps, 1, 16);
                    float s8 = s4 + __shfl_down(s4, 2, 16);   // pairs k..k+3
                    float eH = __shfl_down(cB[f], 3, 16);     // col 2k+7
                    sEv[f] = s8 - eH;      // cols 2k..2k+6
                    sOv[f] = s8 - cA[f];   // cols 2k+1..2k+7
                }

                // ---- temporal 7-ring (slot jj = s % 7) ----
#pragma unroll
                for (int f = 0; f < 4; ++f) {
                    tE[f] += sEv[f] - rE[f][jj];  rE[f][jj] = sEv[f];
                    tO[f] += sOv[f] - rO[f][jj];  rO[f][jj] = sOv[f];
                }

                // ---- emit for t_out = s - 6 ----
                if (s >= 6) {
                    if (vE) loss += ssim1(tE);
                    if (vO) loss += ssim1(tO);
                }
            }
        }
    }

    // ---- block reduction -> global atomic ----
    for (int off = 32; off > 0; off >>= 1)
        loss += __shfl_down(loss, off, 64);
    const int lane = tid & 63;
    const int wid  = tid >> 6;
    if (lane == 0) wsum[wid] = loss;
    __syncthreads();
    if (tid == 0) {
        float s = wsum[0] + wsum[1] + wsum[2] + wsum[3];
        atomicAdd(acc, (double)s);
    }
}

__global__ void ssim3d_finalize(const double* __restrict__ acc,
                                float* __restrict__ out)
{
    out[0] = (float)(acc[0] / (double)NOUT);
}

extern "C" void kernel_launch(void* const* d_in, const int* in_sizes, int n_in,
                              void* d_out, int out_size, void* d_ws, size_t ws_size,
                              hipStream_t stream)
{
    const float* pred   = (const float*)d_in[0];
    const float* targ   = (const float*)d_in[1];
    const float* drange = (const float*)d_in[2];
    float* out  = (float*)d_out;
    double* acc = (double*)d_ws;

    hipMemsetAsync(acc, 0, sizeof(double), stream);

    const int nblocks = B * NTH * NTW;  // 1040
    ssim3d_fused<<<nblocks, 256, 0, stream>>>(pred, targ, drange, acc);
    ssim3d_finalize<<<1, 1, 0, stream>>>(acc, out);
}

// Round 12
// 74.568 us; speedup vs baseline: 5.3326x; 1.1782x over previous
//
#include <hip/hip_runtime.h>

// Fused 3D SSIM, window 7^3, VALID. pred/targ: (4,1,32,320,320) f32.
// R11 skeleton (tile 16h x 26w outputs, full t-range, 1 barrier/slice,
// per-thread pair-colsum, in-register w-gather, temporal 7-ring) with:
//  - p,q interleaved as float4 in LDS -> colsum = 7 ds_read_b128
//  - w-gather via DPP row_shr (VALU) instead of ds_bpermute shuffles.
//    Windows END at thread k's pair: s8 = pairs k-3..k (cols 2k-6..2k+1);
//    even output col 2k-6..2k = s8 - cB(own); odd 2k-5..2k+1 = s8 - shr3(cA).
//  - prefetch issued at slice top for full-slice latency coverage.
// Fields: f0=sum p, f1=sum q, f2=sum p^2+q^2, f3=sum p*q.

#define NPIX 343

constexpr int B = 4, T = 32, H = 320, W = 320;
constexpr int TO = T - 6, HO = H - 6, WO = W - 6;   // 26, 314, 314
constexpr long long NOUT = (long long)B * TO * HO * WO;

constexpr int TH = 16, TW = 26;    // output tile
constexpr int IH = 22, IWP = 16;   // input tile: 22 rows x 16 pair-cols
constexpr int NTH = 20, NTW = 13;  // 20*16 >= 314; 13*26 >= 314
constexpr int NS = 32;             // all t slices per block

template<int N>
__device__ __forceinline__ float row_shr(float x) {
    // lane i (within its 16-lane DPP row) receives lane i-N; OOB -> 0
    return __int_as_float(__builtin_amdgcn_update_dpp(
        0, __float_as_int(x), 0x110 | N, 0xF, 0xF, true));
}

__global__ __launch_bounds__(256) void ssim3d_fused(
    const float* __restrict__ pred,
    const float* __restrict__ targ,
    const float* __restrict__ drange,
    double* __restrict__ acc)
{
    __shared__ float4 spq[2][IH][IWP];   // 11264 B, (p0,p1,q0,q1)
    __shared__ float wsum[4];

    const int bx = blockIdx.x;
    const int b  = bx / (NTH * NTW);
    int rem      = bx % (NTH * NTW);
    const int h0 = (rem / NTW) * TH;
    const int w0 = (rem % NTW) * TW;

    const int tid = threadIdx.x;
    const int oh  = tid >> 4;   // 0..15
    const int k   = tid & 15;   // pair-column 0..15

    const float* pb = pred + (long long)b * T * H * W;
    const float* qb = targ + (long long)b * T * H * W;

    // ---- staging: 352 f4 items = 22 rows x 16 pair-cols ----
    // item0 = tid (all); item1 = 256+tid (tid<96)
    const int r0 = tid >> 4, c0 = tid & 15;
    const int gr0 = min(h0 + r0, H - 1), gc0 = min(w0 + 2 * c0, W - 2);
    const float* g0p = pb + (long long)gr0 * W + gc0;
    const float* g0q = qb + (long long)gr0 * W + gc0;

    const bool act1 = (tid < 96);
    const int r1 = 16 + (tid >> 4), c1 = tid & 15;
    const int gr1 = min(h0 + r1, H - 1), gc1 = min(w0 + 2 * c1, W - 2);
    const float* g1p = pb + (long long)gr1 * W + gc1;
    const float* g1q = qb + (long long)gr1 * W + gc1;

    float2 d0p, d0q, d1p, d1q;
    auto prefetchw = [&](int s) {
        const long long so = (long long)s * H * W;
        d0p = *reinterpret_cast<const float2*>(g0p + so);
        d0q = *reinterpret_cast<const float2*>(g0q + so);
        if (act1) {
            d1p = *reinterpret_cast<const float2*>(g1p + so);
            d1q = *reinterpret_cast<const float2*>(g1q + so);
        }
    };
    auto commitw = [&](int buf) {
        spq[buf][r0][c0] = make_float4(d0p.x, d0p.y, d0q.x, d0q.y);
        if (act1) spq[buf][r1][c1] = make_float4(d1p.x, d1p.y, d1q.x, d1q.y);
    };

    // ---- output mapping: thread k emits local cols 2k-6 (even), 2k-5 (odd)
    const bool vh = (h0 + oh < HO);
    const bool k3 = (k >= 3);
    const bool vE = k3 && vh && (w0 + 2 * k - 6 < WO);
    const bool vO = k3 && vh && (w0 + 2 * k - 5 < WO);

    const float dr  = drange[b];
    const float C1v = (0.01f * dr) * (0.01f * dr);
    const float C2v = (0.03f * dr) * (0.03f * dr);
    const float inv  = 1.0f / (float)NPIX;
    const float covn = (float)NPIX / (float)(NPIX - 1);

    float rE[4][7], rO[4][7], tE[4], tO[4];
#pragma unroll
    for (int f = 0; f < 4; ++f) {
        tE[f] = tO[f] = 0.f;
#pragma unroll
        for (int j = 0; j < 7; ++j) { rE[f][j] = rO[f][j] = 0.f; }
    }
    float loss = 0.f;

    auto ssim1 = [&](const float* tt) {
        float ux  = tt[0] * inv, uy = tt[1] * inv;
        float u2  = tt[2] * inv, uxy = tt[3] * inv;
        float B2 = covn * (u2 - ux * ux - uy * uy) + C2v;
        float A2 = 2.f * covn * (uxy - ux * uy) + C2v;
        float A1 = 2.f * ux * uy + C1v;
        float B1 = ux * ux + uy * uy + C1v;
        return 1.f - __fdividef(A1 * A2, B1 * B2);
    };

    // ---- prologue ----
    prefetchw(0);
    commitw(0);
    prefetchw(1);
    __syncthreads();

    for (int a = 0; a < NS; a += 7) {
#pragma unroll
        for (int jj = 0; jj < 7; ++jj) {
            const int s = a + jj;
            if (s < NS) {
                const int bs = s & 1, bn = bs ^ 1;

                // commit slice s+1 (loaded during slice s-1)
                if (s + 1 < NS) commitw(bn);
                // issue slice s+2's loads now: covered by colsum+barrier+gather
                if (s + 2 < NS) prefetchw(s + 2);

                // ---- per-thread pair-colsum: cols (2k,2k+1), rows oh..oh+6
                float cA[4] = {0.f, 0.f, 0.f, 0.f};
                float cB[4] = {0.f, 0.f, 0.f, 0.f};
#pragma unroll
                for (int dy = 0; dy < 7; ++dy) {
                    float4 v = spq[bs][oh + dy][k];
                    cA[0] += v.x;  cB[0] += v.y;
                    cA[1] += v.z;  cB[1] += v.w;
                    cA[2] = fmaf(v.x, v.x, cA[2]);  cA[2] = fmaf(v.z, v.z, cA[2]);
                    cB[2] = fmaf(v.y, v.y, cB[2]);  cB[2] = fmaf(v.w, v.w, cB[2]);
                    cA[3] = fmaf(v.x, v.z, cA[3]);
                    cB[3] = fmaf(v.y, v.w, cB[3]);
                }

                __syncthreads();   // spq[bn] committed; spq[bs] reads done

                // ---- in-register w-gather via DPP row_shr ----
                float sEv[4], sOv[4];
#pragma unroll
                for (int f = 0; f < 4; ++f) {
                    float ps = cA[f] + cB[f];
                    float t1 = ps + row_shr<1>(ps);
                    float s8 = t1 + row_shr<2>(t1);      // pairs k-3..k
                    float eL = row_shr<3>(cA[f]);        // col 2k-6
                    sEv[f] = s8 - cB[f];                 // cols 2k-6..2k
                    sOv[f] = s8 - eL;                    // cols 2k-5..2k+1
                }

                // ---- temporal 7-ring (slot jj = s % 7) ----
#pragma unroll
                for (int f = 0; f < 4; ++f) {
                    tE[f] += sEv[f] - rE[f][jj];  rE[f][jj] = sEv[f];
                    tO[f] += sOv[f] - rO[f][jj];  rO[f][jj] = sOv[f];
                }

                // ---- emit for t_out = s - 6 ----
                if (s >= 6) {
                    if (vE) loss += ssim1(tE);
                    if (vO) loss += ssim1(tO);
                }
            }
        }
    }

    // ---- block reduction -> global atomic ----
    for (int off = 32; off > 0; off >>= 1)
        loss += __shfl_down(loss, off, 64);
    const int lane = tid & 63;
    const int wid  = tid >> 6;
    if (lane == 0) wsum[wid] = loss;
    __syncthreads();
    if (tid == 0) {
        float s = wsum[0] + wsum[1] + wsum[2] + wsum[3];
        atomicAdd(acc, (double)s);
    }
}

__global__ void ssim3d_finalize(const double* __restrict__ acc,
                                float* __restrict__ out)
{
    out[0] = (float)(acc[0] / (double)NOUT);
}

extern "C" void kernel_launch(void* const* d_in, const int* in_sizes, int n_in,
                              void* d_out, int out_size, void* d_ws, size_t ws_size,
                              hipStream_t stream)
{
    const float* pred   = (const float*)d_in[0];
    const float* targ   = (const float*)d_in[1];
    const float* drange = (const float*)d_in[2];
    float* out  = (float*)d_out;
    double* acc = (double*)d_ws;

    hipMemsetAsync(acc, 0, sizeof(double), stream);

    const int nblocks = B * NTH * NTW;  // 1040
    ssim3d_fused<<<nblocks, 256, 0, stream>>>(pred, targ, drange, acc);
    ssim3d_finalize<<<1, 1, 0, stream>>>(acc, out);
}

// Round 13
// 72.443 us; speedup vs baseline: 5.4890x; 1.0293x over previous
//
#include <hip/hip_runtime.h>

// Fused 3D SSIM, window 7^3, VALID. pred/targ: (4,1,32,320,320) f32.
// R12 skeleton (tile 16h x 26w outputs, full t-range, 1 barrier/slice,
// per-thread pair-colsum from float4-interleaved LDS, DPP row_shr w-gather,
// temporal 7-ring) with:
//  - packed f32 (v2f ext-vector -> v_pk_*_f32) for colsum fields, (E,O) ring,
//    and the SSIM tail (evaluated once on packed (E,O)).
//  - loop peeling: slices 0..6 (no emit), 7..27 (unconditional), 28..31
//    (tail flags compile-time) -> no runtime predicates in the hot loop.
// Fields: f0=sum p, f1=sum q, f2=sum p^2+q^2, f3=sum p*q.

#define NPIX 343

constexpr int B = 4, T = 32, H = 320, W = 320;
constexpr int TO = T - 6, HO = H - 6, WO = W - 6;   // 26, 314, 314
constexpr long long NOUT = (long long)B * TO * HO * WO;

constexpr int TH = 16, TW = 26;    // output tile
constexpr int IH = 22, IWP = 16;   // input tile: 22 rows x 16 pair-cols
constexpr int NTH = 20, NTW = 13;  // 20*16 >= 314; 13*26 >= 314
constexpr int NS = 32;             // all t slices per block

typedef float v2f __attribute__((ext_vector_type(2)));

template<int N>
__device__ __forceinline__ float row_shr(float x) {
    // lane i (within its 16-lane DPP row) receives lane i-N; OOB -> 0
    return __int_as_float(__builtin_amdgcn_update_dpp(
        0, __float_as_int(x), 0x110 | N, 0xF, 0xF, true));
}

__global__ __launch_bounds__(256) void ssim3d_fused(
    const float* __restrict__ pred,
    const float* __restrict__ targ,
    const float* __restrict__ drange,
    double* __restrict__ acc)
{
    __shared__ float4 spq[2][IH][IWP];   // 11264 B, (p0,p1,q0,q1)
    __shared__ float wsum[4];

    const int bx = blockIdx.x;
    const int b  = bx / (NTH * NTW);
    int rem      = bx % (NTH * NTW);
    const int h0 = (rem / NTW) * TH;
    const int w0 = (rem % NTW) * TW;

    const int tid = threadIdx.x;
    const int oh  = tid >> 4;   // 0..15
    const int k   = tid & 15;   // pair-column 0..15

    const float* pb = pred + (long long)b * T * H * W;
    const float* qb = targ + (long long)b * T * H * W;

    // ---- staging: 352 f4 items = 22 rows x 16 pair-cols ----
    const int r0 = tid >> 4, c0 = tid & 15;
    const int gr0 = min(h0 + r0, H - 1), gc0 = min(w0 + 2 * c0, W - 2);
    const float* g0p = pb + (long long)gr0 * W + gc0;
    const float* g0q = qb + (long long)gr0 * W + gc0;

    const bool act1 = (tid < 96);
    const int r1 = 16 + (tid >> 4), c1 = tid & 15;
    const int gr1 = min(h0 + r1, H - 1), gc1 = min(w0 + 2 * c1, W - 2);
    const float* g1p = pb + (long long)gr1 * W + gc1;
    const float* g1q = qb + (long long)gr1 * W + gc1;

    float2 d0p, d0q, d1p, d1q;
    auto prefetchw = [&](int s) {
        const long long so = (long long)s * H * W;
        d0p = *reinterpret_cast<const float2*>(g0p + so);
        d0q = *reinterpret_cast<const float2*>(g0q + so);
        if (act1) {
            d1p = *reinterpret_cast<const float2*>(g1p + so);
            d1q = *reinterpret_cast<const float2*>(g1q + so);
        }
    };
    auto commitw = [&](int buf) {
        spq[buf][r0][c0] = make_float4(d0p.x, d0p.y, d0q.x, d0q.y);
        if (act1) spq[buf][r1][c1] = make_float4(d1p.x, d1p.y, d1q.x, d1q.y);
    };

    // ---- output mapping: thread k emits local cols 2k-6 (even), 2k-5 (odd)
    const bool vh = (h0 + oh < HO);
    const bool k3 = (k >= 3);
    const bool vE = k3 && vh && (w0 + 2 * k - 6 < WO);
    const bool vO = k3 && vh && (w0 + 2 * k - 5 < WO);

    const float dr  = drange[b];
    const float C1s = (0.01f * dr) * (0.01f * dr);
    const float C2s = (0.03f * dr) * (0.03f * dr);
    const float inv  = 1.0f / (float)NPIX;
    const float covn = (float)NPIX / (float)(NPIX - 1);
    const v2f invv  = {inv, inv};
    const v2f C1vv  = {C1s, C1s};
    const v2f C2vv  = {C2s, C2s};
    const v2f covnv = {covn, covn};
    const v2f c2cov = {2.f * covn, 2.f * covn};

    v2f rEO[4][7], tEO[4];
#pragma unroll
    for (int f = 0; f < 4; ++f) {
        tEO[f] = (v2f){0.f, 0.f};
#pragma unroll
        for (int j = 0; j < 7; ++j) rEO[f][j] = (v2f){0.f, 0.f};
    }
    float loss = 0.f;

    // ---- one slice step; all bools compile-time at every call site ----
    auto slice = [&](int s, int jj, bool doEmit, bool doCommit, bool doPrefetch) {
        const int bs = s & 1, bn = bs ^ 1;

        if (doCommit)  commitw(bn);        // slice s+1 (loaded during s-1)
        if (doPrefetch) prefetchw(s + 2);  // covered by colsum+barrier+gather

        // ---- per-thread pair-colsum: cols (2k,2k+1), rows oh..oh+6 ----
        v2f c0 = {0.f, 0.f}, c1v = {0.f, 0.f}, c2 = {0.f, 0.f}, c3 = {0.f, 0.f};
#pragma unroll
        for (int dy = 0; dy < 7; ++dy) {
            float4 v = spq[bs][oh + dy][k];
            v2f vp = {v.x, v.y};
            v2f vq = {v.z, v.w};
            c0 += vp;
            c1v += vq;
            c2 = __builtin_elementwise_fma(vp, vp, c2);
            c2 = __builtin_elementwise_fma(vq, vq, c2);
            c3 = __builtin_elementwise_fma(vp, vq, c3);
        }

        __syncthreads();   // spq[bn] committed; spq[bs] reads done

        // ---- in-register w-gather via DPP row_shr ----
        v2f sv[4];
        {
            v2f cf[4] = {c0, c1v, c2, c3};
#pragma unroll
            for (int f = 0; f < 4; ++f) {
                float ps = cf[f].x + cf[f].y;
                float t1 = ps + row_shr<1>(ps);
                float s8 = t1 + row_shr<2>(t1);      // pairs k-3..k
                float eL = row_shr<3>(cf[f].x);      // col 2k-6
                sv[f].x = s8 - cf[f].y;              // cols 2k-6..2k (even)
                sv[f].y = s8 - eL;                   // cols 2k-5..2k+1 (odd)
            }
        }

        // ---- temporal 7-ring (slot jj = s % 7), packed (E,O) ----
#pragma unroll
        for (int f = 0; f < 4; ++f) {
            tEO[f] += sv[f] - rEO[f][jj];
            rEO[f][jj] = sv[f];
        }

        // ---- SSIM on packed (E,O), emit for t_out = s - 6 ----
        if (doEmit) {
            v2f ux  = tEO[0] * invv;
            v2f uy  = tEO[1] * invv;
            v2f u2  = tEO[2] * invv;
            v2f uxy = tEO[3] * invv;
            v2f m   = __builtin_elementwise_fma(-ux, uy, uxy);
            v2f A2  = __builtin_elementwise_fma(c2cov, m, C2vv);
            v2f nb  = __builtin_elementwise_fma(-ux, ux, u2);
            nb      = __builtin_elementwise_fma(-uy, uy, nb);
            v2f B2  = __builtin_elementwise_fma(covnv, nb, C2vv);
            v2f ux2 = ux + ux;
            v2f A1  = __builtin_elementwise_fma(ux2, uy, C1vv);
            v2f B1  = __builtin_elementwise_fma(
                          ux, ux, __builtin_elementwise_fma(uy, uy, C1vv));
            v2f num = A1 * A2;
            v2f den = B1 * B2;
            float sx = __fdividef(num.x, den.x);
            float sy = __fdividef(num.y, den.y);
            if (vE) loss += 1.f - sx;
            if (vO) loss += 1.f - sy;
        }
    };

    // ---- prologue ----
    prefetchw(0);
    commitw(0);
    prefetchw(1);
    __syncthreads();

    // slices 0..6: ring fill, emit only at s==6
#pragma unroll
    for (int jj = 0; jj < 7; ++jj)
        slice(jj, jj, jj == 6, true, true);

    // slices 7..27: fully unconditional (s+2 <= 29 < 32)
    for (int a = 7; a <= 21; a += 7)
#pragma unroll
        for (int jj = 0; jj < 7; ++jj)
            slice(a + jj, jj, true, true, true);

    // tail: s = 28..31 (flags compile-time)
    slice(28, 0, true, true, true);    // commit 29, prefetch 30
    slice(29, 1, true, true, true);    // commit 30, prefetch 31
    slice(30, 2, true, true, false);   // commit 31
    slice(31, 3, true, false, false);

    // ---- block reduction -> global atomic ----
    for (int off = 32; off > 0; off >>= 1)
        loss += __shfl_down(loss, off, 64);
    const int lane = tid & 63;
    const int wid  = tid >> 6;
    if (lane == 0) wsum[wid] = loss;
    __syncthreads();
    if (tid == 0) {
        float s = wsum[0] + wsum[1] + wsum[2] + wsum[3];
        atomicAdd(acc, (double)s);
    }
}

__global__ void ssim3d_finalize(const double* __restrict__ acc,
                                float* __restrict__ out)
{
    out[0] = (float)(acc[0] / (double)NOUT);
}

extern "C" void kernel_launch(void* const* d_in, const int* in_sizes, int n_in,
                              void* d_out, int out_size, void* d_ws, size_t ws_size,
                              hipStream_t stream)
{
    const float* pred   = (const float*)d_in[0];
    const float* targ   = (const float*)d_in[1];
    const float* drange = (const float*)d_in[2];
    float* out  = (float*)d_out;
    double* acc = (double*)d_ws;

    hipMemsetAsync(acc, 0, sizeof(double), stream);

    const int nblocks = B * NTH * NTW;  // 1040
    ssim3d_fused<<<nblocks, 256, 0, stream>>>(pred, targ, drange, acc);
    ssim3d_finalize<<<1, 1, 0, stream>>>(acc, out);
}